// Round 6
// baseline (83.047 us; speedup 1.0000x reference)
//
#include <hip/hip_runtime.h>

// Batched Kalman filter, fully reduced:
//   B    = H @ phi                  (8x16)   Cphi = C @ phi       (8x16)
//   Sc   = H diag(Q) H^T + diag(R)  (8x8)    CQH  = C diag(Q) H^T (8x8)
//   T    = P0 @ B^T                 (16x8 per element)
//   S    = B @ T + Sc               (8x8 SPD)
//   y    = z - B @ x0
//   w    = S^-1 y                   (lane-parallel GE, no pivoting)
//   out  = Cphi @ (x0 + T w) + CQH @ w
// 8 threads per element (thread i owns rows i, i+8), 32 elements per chunk,
// 256-thread blocks, GRID-STRIDE over chunks: constants derived once per
// block (reads phi/H/C/Q/R direct from global, L2-hot), ONE barrier total,
// then a barrier-free streaming loop — all cross-lane transport (T round-trip
// via LDS b128, solve/gathers via 8-wide shfl) is intra-wave, ds-ordered.
//
// Hard-won structure notes:
//  - plain __launch_bounds__(256): a min-waves hint forced VGPR=40 and
//    ~470 MB of scratch spill traffic in round 2. Never again.
//  - Cross-lane matrix transport (T) via LDS b128 round-trips; per-scalar
//    shuffles for this were ~4x DS-pipe issue and +22 us (round 4).
//  - #pragma unroll 1 on the stream loop: keep the allocator at the natural
//    ~80 VGPR, no software-pipeline register inflation.

#define QFMA(ACC, OFF, A, V) { ACC[(OFF)+0] += (A)*(V).x; ACC[(OFF)+1] += (A)*(V).y; ACC[(OFF)+2] += (A)*(V).z; ACC[(OFF)+3] += (A)*(V).w; }
#define TS 132  // per-element float stride of T buffer (4*33: odd quad -> bijective bank spread)

__global__ __launch_bounds__(256) void kalman_fused6(
    const float* __restrict__ z,
    const float* __restrict__ x0,
    const float* __restrict__ P0,
    const float* __restrict__ phi,
    const float* __restrict__ Hm,
    const float* __restrict__ Cm,
    const float* __restrict__ Qd,
    const float* __restrict__ Rd,
    float* __restrict__ out,
    int bs)
{
    __shared__ __align__(16) float BnS[8 * 20];   // B rows, stride 20
    __shared__ __align__(16) float BTS[16 * 8];   // BTS[k*8+m] = B[m][k] (broadcast reads)
    __shared__ __align__(16) float CpS[8 * 20];   // Cphi rows, stride 20
    __shared__ __align__(16) float CQHS[8 * 8];   // CQH rows
    __shared__ __align__(16) float ScS[8 * 8];    // Sc rows
    __shared__ __align__(16) float x0S[32 * 20];  // per-element x0, stride 20
    __shared__ __align__(16) float Tb[32 * TS];   // per-element T (16 rows x 8)

    const int tid = threadIdx.x;
    const int e = tid >> 3;   // element in chunk (0..31)
    const int i = tid & 7;    // lane in element (0..7)

    // ---- derive per-block constants straight from global (tiny, cache-hot) ----
    if (tid < 128) {
        const int m = tid >> 4, k = tid & 15;
        float bv = 0.f, cv = 0.f;
#pragma unroll
        for (int j = 0; j < 16; ++j) {
            const float pj = phi[j * 16 + k];
            bv += Hm[m * 16 + j] * pj;
            cv += Cm[m * 16 + j] * pj;
        }
        BnS[m * 20 + k] = bv;
        BTS[k * 8 + m]  = bv;
        CpS[m * 20 + k] = cv;
    }
    if (tid < 64) {
        const int i2 = tid >> 3, j2 = tid & 7;
        float sc = (i2 == j2) ? Rd[i2] : 0.f;
        float cq = 0.f;
#pragma unroll
        for (int k = 0; k < 16; ++k) {
            const float qh = Qd[k] * Hm[j2 * 16 + k];
            sc += Hm[i2 * 16 + k] * qh;
            cq += Cm[i2 * 16 + k] * qh;
        }
        ScS[i2 * 8 + j2]  = sc;
        CQHS[i2 * 8 + j2] = cq;
    }
    __syncthreads();  // the ONLY barrier — streaming loop below is barrier-free

    const long stride = (long)gridDim.x * 32;
#pragma unroll 1
    for (long b0 = (long)blockIdx.x * 32; b0 < (long)bs; b0 += stride) {
        const long b = b0 + e;
        if (b >= (long)bs) continue;   // whole 8-lane group skips together

        // ---- per-element loads (8x dwordx4 + 2 + 1, independent, early) ----
        float4 Pq[8];
        {
            const float4* P0v = reinterpret_cast<const float4*>(P0 + (size_t)b * 256);
#pragma unroll
            for (int q = 0; q < 4; ++q) {
                Pq[q]     = P0v[i * 4 + q];
                Pq[q + 4] = P0v[(i + 8) * 4 + q];
            }
        }
        const float x0a = x0[b * 16 + i];
        const float x0b = x0[b * 16 + 8 + i];
        float yv = z[b * 8 + i];
        x0S[e * 20 + i]     = x0a;
        x0S[e * 20 + i + 8] = x0b;

        // ---- T rows i, i+8: T[r][m] = sum_k P0[r][k] * B[m][k] ----
        float t0[8], t1[8];
#pragma unroll
        for (int m = 0; m < 8; ++m) { t0[m] = 0.f; t1[m] = 0.f; }
#pragma unroll
        for (int q = 0; q < 4; ++q) {
            const float4 A = Pq[q], B4 = Pq[q + 4];
            const float a[4] = {A.x, A.y, A.z, A.w};
            const float c[4] = {B4.x, B4.y, B4.z, B4.w};
#pragma unroll
            for (int kk = 0; kk < 4; ++kk) {
                const int k = 4 * q + kk;
                const float4 b0v = *reinterpret_cast<const float4*>(&BTS[k * 8 + 0]);
                const float4 b1v = *reinterpret_cast<const float4*>(&BTS[k * 8 + 4]);
                QFMA(t0, 0, a[kk], b0v) QFMA(t0, 4, a[kk], b1v)
                QFMA(t1, 0, c[kk], b0v) QFMA(t1, 4, c[kk], b1v)
            }
        }
        // stage T (intra-wave round-trip; producer==consumer wave, no barrier)
        *reinterpret_cast<float4*>(&Tb[e * TS + i * 8 + 0]) = make_float4(t0[0], t0[1], t0[2], t0[3]);
        *reinterpret_cast<float4*>(&Tb[e * TS + i * 8 + 4]) = make_float4(t0[4], t0[5], t0[6], t0[7]);
        *reinterpret_cast<float4*>(&Tb[e * TS + (i + 8) * 8 + 0]) = make_float4(t1[0], t1[1], t1[2], t1[3]);
        *reinterpret_cast<float4*>(&Tb[e * TS + (i + 8) * 8 + 4]) = make_float4(t1[4], t1[5], t1[6], t1[7]);

        // ---- B row i -> regs ----
        float br[16];
#pragma unroll
        for (int q = 0; q < 4; ++q) {
            const float4 A = *reinterpret_cast<const float4*>(&BnS[i * 20 + 4 * q]);
            br[4*q+0] = A.x; br[4*q+1] = A.y; br[4*q+2] = A.z; br[4*q+3] = A.w;
        }

        // ---- S row i = Sc[i,:] + B[i,:] @ T ----
        float s[8];
        {
            const float4 c0 = *reinterpret_cast<const float4*>(&ScS[i * 8 + 0]);
            const float4 c1 = *reinterpret_cast<const float4*>(&ScS[i * 8 + 4]);
            s[0]=c0.x; s[1]=c0.y; s[2]=c0.z; s[3]=c0.w; s[4]=c1.x; s[5]=c1.y; s[6]=c1.z; s[7]=c1.w;
        }
#pragma unroll
        for (int j = 0; j < 16; ++j) {
            const float4 ta = *reinterpret_cast<const float4*>(&Tb[e * TS + j * 8 + 0]);
            const float4 tb = *reinterpret_cast<const float4*>(&Tb[e * TS + j * 8 + 4]);
            const float bij = br[j];
            QFMA(s, 0, bij, ta) QFMA(s, 4, bij, tb)
        }

        // ---- y_i = z_i - B[i,:] @ x0 ----
#pragma unroll
        for (int q = 0; q < 4; ++q) {
            const float4 X = *reinterpret_cast<const float4*>(&x0S[e * 20 + 4 * q]);
            yv -= br[4*q+0]*X.x + br[4*q+1]*X.y + br[4*q+2]*X.z + br[4*q+3]*X.w;
        }

        // ---- solve S w = y : lane-parallel GE (S SPD, no pivoting) ----
#pragma unroll
        for (int k = 0; k < 7; ++k) {
            float pr[8];
#pragma unroll
            for (int j = k; j < 8; ++j) pr[j] = __shfl(s[j], k, 8);
            const float py = __shfl(yv, k, 8);
            if (i > k) {
                const float f = s[k] / pr[k];
#pragma unroll
                for (int j = k; j < 8; ++j) s[j] -= f * pr[j];
                yv -= f * py;
            }
        }
        float w[8];
#pragma unroll
        for (int k = 7; k >= 0; --k) {
            const float num = __shfl(yv, k, 8);
            const float den = __shfl(s[k], k, 8);
            const float wk = num / den;
            w[k] = wk;
            if (i < k) yv -= s[k] * wk;
        }

        // ---- u rows = x0 + T w (registers) ----
        float th0 = 0.f, th1 = 0.f;
#pragma unroll
        for (int m = 0; m < 8; ++m) { th0 += t0[m] * w[m]; th1 += t1[m] * w[m]; }
        const float u0v = x0a + th0;
        const float u1v = x0b + th1;

        // ---- gather full u via shuffles ----
        float uv[16];
#pragma unroll
        for (int j = 0; j < 8; ++j) {
            uv[j]     = __shfl(u0v, j, 8);
            uv[j + 8] = __shfl(u1v, j, 8);
        }

        // ---- out[b][i] = Cphi[i,:] @ u + CQH[i,:] @ w ----
        float oc = 0.f;
#pragma unroll
        for (int q = 0; q < 4; ++q) {
            const float4 A = *reinterpret_cast<const float4*>(&CpS[i * 20 + 4 * q]);
            oc += A.x*uv[4*q+0] + A.y*uv[4*q+1] + A.z*uv[4*q+2] + A.w*uv[4*q+3];
        }
        {
            const float4 q0 = *reinterpret_cast<const float4*>(&CQHS[i * 8 + 0]);
            const float4 q1 = *reinterpret_cast<const float4*>(&CQHS[i * 8 + 4]);
            oc += q0.x*w[0] + q0.y*w[1] + q0.z*w[2] + q0.w*w[3]
                + q1.x*w[4] + q1.y*w[5] + q1.z*w[6] + q1.w*w[7];
        }
        out[b * 8 + i] = oc;
    }
}

extern "C" void kernel_launch(void* const* d_in, const int* in_sizes, int n_in,
                              void* d_out, int out_size, void* d_ws, size_t ws_size,
                              hipStream_t stream)
{
    const float* z   = (const float*)d_in[0];
    const float* x0  = (const float*)d_in[1];
    const float* P0  = (const float*)d_in[2];
    const float* phi = (const float*)d_in[3];
    const float* H   = (const float*)d_in[4];
    const float* C   = (const float*)d_in[5];
    const float* Qd  = (const float*)d_in[6];
    const float* Rd  = (const float*)d_in[7];
    float* out = (float*)d_out;

    const int bs = in_sizes[0] / 8;          // z is [bs, 8]
    const int chunks = (bs + 31) / 32;
    const int blocks = (chunks < 1536) ? chunks : 1536;  // 6 resident blocks/CU x 256 CU
    hipLaunchKernelGGL(kalman_fused6, dim3(blocks), dim3(256), 0, stream,
                       z, x0, P0, phi, H, C, Qd, Rd, out, bs);
}

// Round 7
// 68.106 us; speedup vs baseline: 1.2194x; 1.2194x over previous
//
#include <hip/hip_runtime.h>

// Batched Kalman filter, fully reduced:
//   B    = H @ phi                  (8x16)   Cphi = C @ phi       (8x16)
//   Sc   = H diag(Q) H^T + diag(R)  (8x8)    CQH  = C diag(Q) H^T (8x8)
//   T    = P0 @ B^T                 (16x8 per element)
//   S    = B @ T + Sc               (8x8 SPD, min-eig >= R = 0.1)
//   y    = z - B @ x0
//   w    = S^-1 y                   (REDUNDANT per-lane Cholesky, in-register)
//   out  = Cphi @ (x0 + T w) + CQH @ w
// 8 threads per element (thread i owns rows i, i+8), 32 elements per
// 256-thread block, 8192 blocks. ONE barrier (constants). All cross-lane
// transport is intra-wave LDS b128 round-trips (ds-ordered, barrier-free).
//
// Hard-won structure notes:
//  - plain __launch_bounds__(256): a min-waves hint forced VGPR=40 and
//    ~470 MB of scratch spill traffic in round 2. Never again.
//  - Cross-lane matrix transport via LDS b128; per-scalar shuffles were ~4x
//    DS-pipe issue and +22 us (round 4).
//  - Round 7: the 58-shfl lane-cooperative GE solve (~15 dependent DS hops
//    x ~120cyc latency + divergence + 15 precise divs) is replaced by an
//    LDS round-trip of S/y + fully in-register redundant Cholesky per lane
//    (zero cross-lane, zero divergence, v_rsq instead of div).
//  - Grid-stride (r6) was +3us vs independent blocks: reverted.

#define QFMA(ACC, OFF, A, V) { ACC[(OFF)+0] += (A)*(V).x; ACC[(OFF)+1] += (A)*(V).y; ACC[(OFF)+2] += (A)*(V).z; ACC[(OFF)+3] += (A)*(V).w; }
#define TS 132  // Tb element stride (words): 132 % 32 == 4 -> groups hit distinct banks
#define XS 28   // x0S element stride (words): 28 % 32 == 28 -> distinct group banks
#define TRI(a,k) ((a)*((a)+1)/2 + (k))

__global__ __launch_bounds__(256) void kalman_fused7(
    const float* __restrict__ z,
    const float* __restrict__ x0,
    const float* __restrict__ P0,
    const float* __restrict__ phi,
    const float* __restrict__ Hm,
    const float* __restrict__ Cm,
    const float* __restrict__ Qd,
    const float* __restrict__ Rd,
    float* __restrict__ out,
    int bs)
{
    __shared__ __align__(16) float BnS[8 * 20];   // B rows, stride 20
    __shared__ __align__(16) float BTS[16 * 8];   // BTS[k*8+m] = B[m][k] (wave-uniform reads)
    __shared__ __align__(16) float CpS[8 * 20];   // Cphi rows, stride 20
    __shared__ __align__(16) float CQHS[8 * 8];   // CQH rows
    __shared__ __align__(16) float ScS[8 * 8];    // Sc rows
    __shared__ __align__(16) float x0S[32 * XS];  // words 0..15: x0 (later u); 16..23: y
    __shared__ __align__(16) float Tb[32 * TS];   // words 0..127: T rows (rows 0..7 later reused for S)

    const int tid = threadIdx.x;
    const int e = tid >> 3;   // element in block (0..31)
    const int i = tid & 7;    // lane in element (0..7)
    long b = (long)blockIdx.x * 32 + e;
    const bool valid = (b < (long)bs);
    if (!valid) b = (long)bs - 1;

    // ---- per-element global loads issued first (latency hides under derive) ----
    float4 Pq[8];
    {
        const float4* P0v = reinterpret_cast<const float4*>(P0 + (size_t)b * 256);
#pragma unroll
        for (int q = 0; q < 4; ++q) {
            Pq[q]     = P0v[i * 4 + q];
            Pq[q + 4] = P0v[(i + 8) * 4 + q];
        }
    }
    const float x0a = x0[b * 16 + i];
    const float x0b = x0[b * 16 + 8 + i];
    float yv = z[b * 8 + i];
    x0S[e * XS + i]     = x0a;
    x0S[e * XS + i + 8] = x0b;

    // ---- derive per-block constants straight from global (tiny, cache-hot) ----
    if (tid < 128) {
        const int m = tid >> 4, k = tid & 15;
        float bv = 0.f, cv = 0.f;
#pragma unroll
        for (int j = 0; j < 16; ++j) {
            const float pj = phi[j * 16 + k];
            bv += Hm[m * 16 + j] * pj;
            cv += Cm[m * 16 + j] * pj;
        }
        BnS[m * 20 + k] = bv;
        BTS[k * 8 + m]  = bv;
        CpS[m * 20 + k] = cv;
    }
    if (tid < 64) {
        const int i2 = tid >> 3, j2 = tid & 7;
        float sc = (i2 == j2) ? Rd[i2] : 0.f;
        float cq = 0.f;
#pragma unroll
        for (int k = 0; k < 16; ++k) {
            const float qh = Qd[k] * Hm[j2 * 16 + k];
            sc += Hm[i2 * 16 + k] * qh;
            cq += Cm[i2 * 16 + k] * qh;
        }
        ScS[i2 * 8 + j2]  = sc;
        CQHS[i2 * 8 + j2] = cq;
    }
    __syncthreads();  // the ONLY barrier

    // ---- T rows i, i+8: T[r][m] = sum_k P0[r][k] * B[m][k] ----
    float t0[8], t1[8];
#pragma unroll
    for (int m = 0; m < 8; ++m) { t0[m] = 0.f; t1[m] = 0.f; }
#pragma unroll
    for (int q = 0; q < 4; ++q) {
        const float4 A = Pq[q], B4 = Pq[q + 4];
        const float a[4] = {A.x, A.y, A.z, A.w};
        const float c[4] = {B4.x, B4.y, B4.z, B4.w};
#pragma unroll
        for (int kk = 0; kk < 4; ++kk) {
            const int k = 4 * q + kk;
            const float4 b0v = *reinterpret_cast<const float4*>(&BTS[k * 8 + 0]);
            const float4 b1v = *reinterpret_cast<const float4*>(&BTS[k * 8 + 4]);
            QFMA(t0, 0, a[kk], b0v) QFMA(t0, 4, a[kk], b1v)
            QFMA(t1, 0, c[kk], b0v) QFMA(t1, 4, c[kk], b1v)
        }
    }
    // stage T (intra-wave round-trip; producer==consumer wave, no barrier)
    *reinterpret_cast<float4*>(&Tb[e * TS + i * 8 + 0]) = make_float4(t0[0], t0[1], t0[2], t0[3]);
    *reinterpret_cast<float4*>(&Tb[e * TS + i * 8 + 4]) = make_float4(t0[4], t0[5], t0[6], t0[7]);
    *reinterpret_cast<float4*>(&Tb[e * TS + (i + 8) * 8 + 0]) = make_float4(t1[0], t1[1], t1[2], t1[3]);
    *reinterpret_cast<float4*>(&Tb[e * TS + (i + 8) * 8 + 4]) = make_float4(t1[4], t1[5], t1[6], t1[7]);

    // ---- B row i -> regs ----
    float br[16];
#pragma unroll
    for (int q = 0; q < 4; ++q) {
        const float4 A = *reinterpret_cast<const float4*>(&BnS[i * 20 + 4 * q]);
        br[4*q+0] = A.x; br[4*q+1] = A.y; br[4*q+2] = A.z; br[4*q+3] = A.w;
    }

    // ---- S row i = Sc[i,:] + B[i,:] @ T (reads ALL T rows, broadcast in group) ----
    float s[8];
    {
        const float4 c0 = *reinterpret_cast<const float4*>(&ScS[i * 8 + 0]);
        const float4 c1 = *reinterpret_cast<const float4*>(&ScS[i * 8 + 4]);
        s[0]=c0.x; s[1]=c0.y; s[2]=c0.z; s[3]=c0.w; s[4]=c1.x; s[5]=c1.y; s[6]=c1.z; s[7]=c1.w;
    }
#pragma unroll
    for (int j = 0; j < 16; ++j) {
        const float4 ta = *reinterpret_cast<const float4*>(&Tb[e * TS + j * 8 + 0]);
        const float4 tb = *reinterpret_cast<const float4*>(&Tb[e * TS + j * 8 + 4]);
        const float bij = br[j];
        QFMA(s, 0, bij, ta) QFMA(s, 4, bij, tb)
    }

    // ---- y_i = z_i - B[i,:] @ x0 ----
#pragma unroll
    for (int q = 0; q < 4; ++q) {
        const float4 X = *reinterpret_cast<const float4*>(&x0S[e * XS + 4 * q]);
        yv -= br[4*q+0]*X.x + br[4*q+1]*X.y + br[4*q+2]*X.z + br[4*q+3]*X.w;
    }

    // ---- publish S row (reuse Tb rows 0-7: all T reads above are done) and y ----
    *reinterpret_cast<float4*>(&Tb[e * TS + i * 8 + 0]) = make_float4(s[0], s[1], s[2], s[3]);
    *reinterpret_cast<float4*>(&Tb[e * TS + i * 8 + 4]) = make_float4(s[4], s[5], s[6], s[7]);
    x0S[e * XS + 16 + i] = yv;

    // ---- read S lower triangle (12 b128 broadcast reads) + full y ----
    float L[36];
#pragma unroll
    for (int a = 0; a < 8; ++a) {
        const float4 q0 = *reinterpret_cast<const float4*>(&Tb[e * TS + a * 8 + 0]);
        L[TRI(a,0)] = q0.x;
        if (a >= 1) L[TRI(a,1)] = q0.y;
        if (a >= 2) L[TRI(a,2)] = q0.z;
        if (a >= 3) L[TRI(a,3)] = q0.w;
        if (a >= 4) {
            const float4 q1 = *reinterpret_cast<const float4*>(&Tb[e * TS + a * 8 + 4]);
            L[TRI(a,4)] = q1.x;
            if (a >= 5) L[TRI(a,5)] = q1.y;
            if (a >= 6) L[TRI(a,6)] = q1.z;
            if (a >= 7) L[TRI(a,7)] = q1.w;
        }
    }
    float yf[8];
    {
        const float4 ya = *reinterpret_cast<const float4*>(&x0S[e * XS + 16]);
        const float4 yb = *reinterpret_cast<const float4*>(&x0S[e * XS + 20]);
        yf[0]=ya.x; yf[1]=ya.y; yf[2]=ya.z; yf[3]=ya.w;
        yf[4]=yb.x; yf[5]=yb.y; yf[6]=yb.z; yf[7]=yb.w;
    }

    // ---- redundant in-register Cholesky (diag slots hold 1/sqrt after step) ----
#pragma unroll
    for (int k = 0; k < 8; ++k) {
        const float inv = __builtin_amdgcn_rsqf(L[TRI(k,k)]);
        L[TRI(k,k)] = inv;
#pragma unroll
        for (int a = k + 1; a < 8; ++a) L[TRI(a,k)] *= inv;
#pragma unroll
        for (int a = k + 1; a < 8; ++a) {
#pragma unroll
            for (int m = k + 1; m <= a; ++m)
                L[TRI(a,m)] -= L[TRI(a,k)] * L[TRI(m,k)];
        }
    }
    // forward solve L y' = y (in place), then back solve L^T w = y'
#pragma unroll
    for (int a = 0; a < 8; ++a) {
        float t = yf[a];
#pragma unroll
        for (int j = 0; j < a; ++j) t -= L[TRI(a,j)] * yf[j];
        yf[a] = t * L[TRI(a,a)];
    }
    float w[8];
#pragma unroll
    for (int a = 7; a >= 0; --a) {
        float t = yf[a];
#pragma unroll
        for (int j = a + 1; j < 8; ++j) t -= L[TRI(j,a)] * w[j];
        w[a] = t * L[TRI(a,a)];
    }

    // ---- u rows = x0 + T w (registers), publish u (x0S words 0-15 reusable) ----
    float th0 = 0.f, th1 = 0.f;
#pragma unroll
    for (int m = 0; m < 8; ++m) { th0 += t0[m] * w[m]; th1 += t1[m] * w[m]; }
    x0S[e * XS + i]     = x0a + th0;
    x0S[e * XS + i + 8] = x0b + th1;

    // ---- out[b][i] = Cphi[i,:] @ u + CQH[i,:] @ w ----
    float oc = 0.f;
#pragma unroll
    for (int q = 0; q < 4; ++q) {
        const float4 A = *reinterpret_cast<const float4*>(&CpS[i * 20 + 4 * q]);
        const float4 U = *reinterpret_cast<const float4*>(&x0S[e * XS + 4 * q]);
        oc += A.x*U.x + A.y*U.y + A.z*U.z + A.w*U.w;
    }
    {
        const float4 q0 = *reinterpret_cast<const float4*>(&CQHS[i * 8 + 0]);
        const float4 q1 = *reinterpret_cast<const float4*>(&CQHS[i * 8 + 4]);
        oc += q0.x*w[0] + q0.y*w[1] + q0.z*w[2] + q0.w*w[3]
            + q1.x*w[4] + q1.y*w[5] + q1.z*w[6] + q1.w*w[7];
    }
    if (valid) out[b * 8 + i] = oc;
}

extern "C" void kernel_launch(void* const* d_in, const int* in_sizes, int n_in,
                              void* d_out, int out_size, void* d_ws, size_t ws_size,
                              hipStream_t stream)
{
    const float* z   = (const float*)d_in[0];
    const float* x0  = (const float*)d_in[1];
    const float* P0  = (const float*)d_in[2];
    const float* phi = (const float*)d_in[3];
    const float* H   = (const float*)d_in[4];
    const float* C   = (const float*)d_in[5];
    const float* Qd  = (const float*)d_in[6];
    const float* Rd  = (const float*)d_in[7];
    float* out = (float*)d_out;

    const int bs = in_sizes[0] / 8;          // z is [bs, 8]
    const int blocks = (bs + 31) / 32;       // 32 elements per block
    hipLaunchKernelGGL(kalman_fused7, dim3(blocks), dim3(256), 0, stream,
                       z, x0, P0, phi, H, C, Qd, Rd, out, bs);
}